// Round 1
// baseline (720.745 us; speedup 1.0000x reference)
//
#include <hip/hip_runtime.h>

#define N_NODES 65536
#define B_G     16
#define NPG_    4096
#define H_H     2
#define D_D     64
#define HD      128
#define E_E     524288
#define D_OUT   64

// ---------------- degree / CSR build ----------------

__global__ void deg_kernel(const int* __restrict__ col, int* __restrict__ degi) {
    int e = blockIdx.x * 256 + threadIdx.x;
    if (e < E_E) atomicAdd(&degi[col[e]], 1);
}

__global__ void dinv_kernel(const int* __restrict__ degi, float* __restrict__ dinv) {
    int n = blockIdx.x * 256 + threadIdx.x;
    if (n < N_NODES) {
        int d = degi[n];
        dinv[n] = (d > 0) ? (1.0f / sqrtf((float)d)) : 0.0f;
    }
}

__global__ void scan1(const int* __restrict__ degi, int* __restrict__ ptr,
                      int* __restrict__ bsums) {
    __shared__ int lds[256];
    int t = threadIdx.x;
    int i = blockIdx.x * 256 + t;
    int v = degi[i];
    lds[t] = v;
    __syncthreads();
    for (int off = 1; off < 256; off <<= 1) {
        int tmp = (t >= off) ? lds[t - off] : 0;
        __syncthreads();
        lds[t] += tmp;
        __syncthreads();
    }
    ptr[i] = lds[t] - v;                 // block-local exclusive
    if (t == 255) bsums[blockIdx.x] = lds[255];
}

__global__ void scan2(int* __restrict__ bsums) {
    __shared__ int lds[256];
    int t = threadIdx.x;
    int v = bsums[t];
    lds[t] = v;
    __syncthreads();
    for (int off = 1; off < 256; off <<= 1) {
        int tmp = (t >= off) ? lds[t - off] : 0;
        __syncthreads();
        lds[t] += tmp;
        __syncthreads();
    }
    bsums[t] = lds[t] - v;               // exclusive block offsets
}

__global__ void scan3(int* __restrict__ ptr, const int* __restrict__ bsums) {
    int i = blockIdx.x * 256 + threadIdx.x;
    ptr[i] += bsums[blockIdx.x];
    if (i == 0) ptr[N_NODES] = E_E;
}

__global__ void scatter_kernel(const int* __restrict__ row, const int* __restrict__ col,
                               const int* __restrict__ ptr, int* __restrict__ cursor,
                               const float* __restrict__ dinv,
                               int* __restrict__ erow, float* __restrict__ edge_val) {
    int e = blockIdx.x * 256 + threadIdx.x;
    if (e < E_E) {
        int c = col[e], r = row[e];
        int p = ptr[c] + atomicAdd(&cursor[c], 1);
        erow[p] = r;
        edge_val[p] = dinv[c] * dinv[r];
    }
}

// ---------------- q/k projection ----------------
// 512 blocks x 256 thr; block handles 128 nodes; thr<128 -> q col t, else k col t-128.
__global__ __launch_bounds__(256) void proj_kernel(
    const float* __restrict__ x,
    const float* __restrict__ Wq, const float* __restrict__ bq,
    const float* __restrict__ Wk, const float* __restrict__ bk,
    float* __restrict__ qs, float* __restrict__ ks) {
    __shared__ float xl[128 * 64];
    int t = threadIdx.x;
    int nb = blockIdx.x;
    const float4* x4 = (const float4*)(x + nb * 128 * 64);
    float4* xl4 = (float4*)xl;
    for (int i = t; i < 128 * 64 / 4; i += 256) xl4[i] = x4[i];
    __syncthreads();

    int col = t & 127;
    const float* W = (t < 128) ? Wq : Wk;
    float bias = (t < 128) ? bq[col] : bk[col];
    float* outp = (t < 128) ? qs : ks;
    float wc[64];
#pragma unroll
    for (int kk = 0; kk < 64; ++kk) wc[kk] = W[kk * 128 + col];

    for (int i = 0; i < 128; ++i) {
        const float4* xr = (const float4*)(xl + i * 64);
        float acc = bias;
#pragma unroll
        for (int k4 = 0; k4 < 16; ++k4) {
            float4 v = xr[k4];
            acc += v.x * wc[4 * k4] + v.y * wc[4 * k4 + 1] +
                   v.z * wc[4 * k4 + 2] + v.w * wc[4 * k4 + 3];
        }
        outp[(nb * 128 + i) * 128 + col] = acc;
    }
}

// ---------------- L2 normalize q,k per (node,head): one wave per pair ----------------
__global__ __launch_bounds__(256) void norm_kernel(float* __restrict__ qs,
                                                   float* __restrict__ ks) {
    int wid = (blockIdx.x * 256 + threadIdx.x) >> 6;   // (n,h) pair
    int lane = threadIdx.x & 63;
    int idx = wid * 64 + lane;
    float qv = qs[idx], kv = ks[idx];
    float q2 = qv * qv, k2 = kv * kv;
#pragma unroll
    for (int off = 32; off > 0; off >>= 1) {
        q2 += __shfl_xor(q2, off);
        k2 += __shfl_xor(k2, off);
    }
    qs[idx] = qv * rsqrtf(q2);
    ks[idx] = kv * rsqrtf(k2);
}

// ---------------- kvs = K^T X per (b,h); plus ksum, xsum ----------------
// grid 256: (bh, chunk of 512 nodes); 256 thr as 16x16, each 4x4 tile.
__global__ __launch_bounds__(256) void kvs_kernel(
    const float* __restrict__ ks, const float* __restrict__ x,
    float* __restrict__ kvs, float* __restrict__ ksum, float* __restrict__ xsum) {
    int bid = blockIdx.x;
    int chunk = bid & 7;
    int bh = bid >> 3;
    int b = bh >> 1, h = bh & 1;
    int t = threadIdx.x;
    int mrow = t >> 4, dcol = t & 15;
    int m0 = mrow * 4, d0 = dcol * 4;
    __shared__ float kl[32 * 64];
    __shared__ float xl[32 * 64];
    float acc[4][4] = {{0}};
    float ksacc[4] = {0, 0, 0, 0};
    float xsacc[4] = {0, 0, 0, 0};
    int node0 = b * NPG_ + chunk * 512;
    for (int s = 0; s < 16; ++s) {
        int nb = node0 + s * 32;
        for (int i = t; i < 512; i += 256) {
            int l = i >> 4, q = i & 15;
            ((float4*)kl)[i] = *(const float4*)(ks + (size_t)(nb + l) * 128 + h * 64 + q * 4);
        }
        const float4* xg = (const float4*)(x + (size_t)nb * 64);
        for (int i = t; i < 512; i += 256) ((float4*)xl)[i] = xg[i];
        __syncthreads();
        for (int l = 0; l < 32; ++l) {
            float4 kv = *(float4*)(kl + l * 64 + m0);
            float4 xv = *(float4*)(xl + l * 64 + d0);
            float kk[4] = {kv.x, kv.y, kv.z, kv.w};
            float xx[4] = {xv.x, xv.y, xv.z, xv.w};
#pragma unroll
            for (int i = 0; i < 4; ++i)
#pragma unroll
                for (int j = 0; j < 4; ++j) acc[i][j] += kk[i] * xx[j];
            if (dcol == 0) {
#pragma unroll
                for (int i = 0; i < 4; ++i) ksacc[i] += kk[i];
            }
            if (mrow == 0) {
#pragma unroll
                for (int j = 0; j < 4; ++j) xsacc[j] += xx[j];
            }
        }
        __syncthreads();
    }
#pragma unroll
    for (int i = 0; i < 4; ++i)
#pragma unroll
        for (int j = 0; j < 4; ++j)
            atomicAdd(&kvs[(bh * 64 + m0 + i) * 64 + d0 + j], acc[i][j]);
    if (dcol == 0) {
#pragma unroll
        for (int i = 0; i < 4; ++i) atomicAdd(&ksum[bh * 64 + m0 + i], ksacc[i]);
    }
    if (mrow == 0 && h == 0) {
#pragma unroll
        for (int j = 0; j < 4; ++j) atomicAdd(&xsum[b * 64 + d0 + j], xsacc[j]);
    }
}

// ---------------- attention output (loop-invariant): one wave per (n,h) ----------------
__global__ __launch_bounds__(256) void attn_kernel(
    const float* __restrict__ qs, const float* __restrict__ kvs,
    const float* __restrict__ ksum, const float* __restrict__ xsum,
    float* __restrict__ attn) {
    int wid = (blockIdx.x * 256 + threadIdx.x) >> 6;   // (n,h)
    int lane = threadIdx.x & 63;
    int n = wid >> 1, h = wid & 1;
    int b = n >> 12;                                    // NPG=4096
    int bh = b * 2 + h;
    float qv = qs[wid * 64 + lane];
    float den = qv * ksum[bh * 64 + lane];
#pragma unroll
    for (int off = 32; off > 0; off >>= 1) den += __shfl_xor(den, off);
    den += 16.0f;                                       // + float(B)
    const float* kv = kvs + bh * 4096;
    float num = 0.f;
#pragma unroll
    for (int m = 0; m < 64; ++m) {
        float qm = __shfl(qv, m);
        num += qm * kv[m * 64 + lane];
    }
    num += xsum[b * 64 + lane];
    attn[wid * 64 + lane] = num / den;
}

// ---------------- xs init (broadcast x over heads) ----------------
__global__ void xinit_kernel(const float* __restrict__ x, float* __restrict__ xs) {
    int i = blockIdx.x * 256 + threadIdx.x;  // over N*HD
    xs[i] = x[(i >> 7) * 64 + (i & 63)];
}

// ---------------- GCN step: one wave per node, float2 per lane ----------------
__global__ __launch_bounds__(256) void gcn_kernel(
    const float* __restrict__ xin, const float* __restrict__ attn,
    const int* __restrict__ ptr, const int* __restrict__ erow,
    const float* __restrict__ edge_val, float* __restrict__ xout) {
    int t = threadIdx.x;
    int n = blockIdx.x * 4 + (t >> 6);
    int lane = t & 63;
    int e0 = ptr[n], e1 = ptr[n + 1];
    float2 acc = make_float2(0.f, 0.f);
    for (int e = e0; e < e1; ++e) {
        int r = erow[e];
        float v = edge_val[e];
        float2 xv = *(const float2*)(xin + (size_t)r * 128 + lane * 2);
        acc.x += v * xv.x;
        acc.y += v * xv.y;
    }
    size_t idx = (size_t)n * 128 + lane * 2;
    float2 self = *(const float2*)(xin + idx);
    float2 at = *(const float2*)(attn + idx);
    float2 o;
    o.x = self.x + 0.5f * acc.x + 0.5f * at.x;
    o.y = self.y + 0.5f * acc.y + 0.5f * at.y;
    *(float2*)(xout + idx) = o;
}

// ---------------- output projection: (xs @ Wo + bo)/H ----------------
// 1024 blocks x 64 nodes each; 256 thr = 4 nodes x 64 cols.
__global__ __launch_bounds__(256) void out_kernel(
    const float* __restrict__ xs, const float* __restrict__ Wo,
    const float* __restrict__ bo, float* __restrict__ out) {
    __shared__ float wl[128 * 64];
    __shared__ float bl[64];
    int t = threadIdx.x;
    for (int i = t; i < 128 * 64 / 4; i += 256) ((float4*)wl)[i] = ((const float4*)Wo)[i];
    if (t < 64) bl[t] = bo[t];
    __syncthreads();
    int j = t & 63, ng = t >> 6;
    int nbase = blockIdx.x * 64;
    for (int it = 0; it < 16; ++it) {
        int n = nbase + it * 4 + ng;
        const float4* xr4 = (const float4*)(xs + (size_t)n * 128);
        float acc = bl[j];
#pragma unroll
        for (int k4 = 0; k4 < 32; ++k4) {
            float4 v = xr4[k4];
            acc += v.x * wl[(4 * k4 + 0) * 64 + j] + v.y * wl[(4 * k4 + 1) * 64 + j] +
                   v.z * wl[(4 * k4 + 2) * 64 + j] + v.w * wl[(4 * k4 + 3) * 64 + j];
        }
        out[(size_t)n * 64 + j] = acc * 0.5f;   // 1/H
    }
}

// ---------------- launch ----------------

extern "C" void kernel_launch(void* const* d_in, const int* in_sizes, int n_in,
                              void* d_out, int out_size, void* d_ws, size_t ws_size,
                              hipStream_t stream) {
    const float* x  = (const float*)d_in[0];
    const int* ei   = (const int*)d_in[1];
    const float* Wq = (const float*)d_in[3];
    const float* bq = (const float*)d_in[4];
    const float* Wk = (const float*)d_in[5];
    const float* bk = (const float*)d_in[6];
    const float* Wo = (const float*)d_in[7];
    const float* bo = (const float*)d_in[8];
    float* out = (float*)d_out;

    const int* row = ei;
    const int* col = ei + E_E;

    // workspace layout (floats/ints, ~106 MB total)
    float* qs    = (float*)d_ws;                 // N*HD      (later xsA)
    float* ksatt = qs + (size_t)N_NODES * HD;    // N*HD      (ks, later attn)
    float* xsB   = ksatt + (size_t)N_NODES * HD; // N*HD
    float* kvs   = xsB + (size_t)N_NODES * HD;   // 32*64*64 = 131072
    float* ksum  = kvs + 131072;                 // 2048
    float* xsum  = ksum + 2048;                  // 1024
    float* dinv  = xsum + 1024;                  // N
    int* degi    = (int*)(dinv + N_NODES);       // N
    int* ptr     = degi + N_NODES;               // N+1
    int* bsums   = ptr + N_NODES + 1;            // 256 (+pad)
    int* erow    = bsums + 512;                  // E
    float* edge_val = (float*)(erow + E_E);      // E

    // zero accumulators
    hipMemsetAsync(degi, 0, (size_t)N_NODES * 4, stream);
    hipMemsetAsync(kvs, 0, (size_t)(131072 + 2048 + 1024) * 4, stream);

    // CSR build
    deg_kernel<<<E_E / 256, 256, 0, stream>>>(col, degi);
    dinv_kernel<<<N_NODES / 256, 256, 0, stream>>>(degi, dinv);
    scan1<<<N_NODES / 256, 256, 0, stream>>>(degi, ptr, bsums);
    scan2<<<1, 256, 0, stream>>>(bsums);
    scan3<<<N_NODES / 256, 256, 0, stream>>>(ptr, bsums);
    hipMemsetAsync(degi, 0, (size_t)N_NODES * 4, stream);   // reuse as cursor
    scatter_kernel<<<E_E / 256, 256, 0, stream>>>(row, col, ptr, degi, dinv, erow, edge_val);

    // projections + normalize
    proj_kernel<<<512, 256, 0, stream>>>(x, Wq, bq, Wk, bk, qs, ksatt);
    norm_kernel<<<(N_NODES * H_H) / 4, 256, 0, stream>>>(qs, ksatt);

    // attention (loop-invariant)
    kvs_kernel<<<256, 256, 0, stream>>>(ksatt, x, kvs, ksum, xsum);
    attn_kernel<<<(N_NODES * H_H) / 4, 256, 0, stream>>>(qs, kvs, ksum, xsum, ksatt);

    // xs init into qs region (qs no longer needed), then 4 GCN steps ping-pong
    xinit_kernel<<<(N_NODES * HD) / 256, 256, 0, stream>>>(x, qs);
    gcn_kernel<<<N_NODES / 4, 256, 0, stream>>>(qs, ksatt, ptr, erow, edge_val, xsB);
    gcn_kernel<<<N_NODES / 4, 256, 0, stream>>>(xsB, ksatt, ptr, erow, edge_val, qs);
    gcn_kernel<<<N_NODES / 4, 256, 0, stream>>>(qs, ksatt, ptr, erow, edge_val, xsB);
    gcn_kernel<<<N_NODES / 4, 256, 0, stream>>>(xsB, ksatt, ptr, erow, edge_val, qs);

    // output projection
    out_kernel<<<1024, 256, 0, stream>>>(qs, Wo, bo, out);
}

// Round 2
// 615.342 us; speedup vs baseline: 1.1713x; 1.1713x over previous
//
#include <hip/hip_runtime.h>

#define N_NODES 65536
#define B_G     16
#define NPG_    4096
#define H_H     2
#define D_D     64
#define HD      128
#define E_E     524288
#define D_OUT   64

// ---------------- degree / CSR build ----------------

__global__ void deg_kernel(const int* __restrict__ col, int* __restrict__ degi) {
    int e = blockIdx.x * 256 + threadIdx.x;
    if (e < E_E) atomicAdd(&degi[col[e]], 1);
}

__global__ void dinv_kernel(const int* __restrict__ degi, float* __restrict__ dinv) {
    int n = blockIdx.x * 256 + threadIdx.x;
    if (n < N_NODES) {
        int d = degi[n];
        dinv[n] = (d > 0) ? (1.0f / sqrtf((float)d)) : 0.0f;
    }
}

__global__ void scan1(const int* __restrict__ degi, int* __restrict__ ptr,
                      int* __restrict__ bsums) {
    __shared__ int lds[256];
    int t = threadIdx.x;
    int i = blockIdx.x * 256 + t;
    int v = degi[i];
    lds[t] = v;
    __syncthreads();
    for (int off = 1; off < 256; off <<= 1) {
        int tmp = (t >= off) ? lds[t - off] : 0;
        __syncthreads();
        lds[t] += tmp;
        __syncthreads();
    }
    ptr[i] = lds[t] - v;                 // block-local exclusive
    if (t == 255) bsums[blockIdx.x] = lds[255];
}

__global__ void scan2(int* __restrict__ bsums) {
    __shared__ int lds[256];
    int t = threadIdx.x;
    int v = bsums[t];
    lds[t] = v;
    __syncthreads();
    for (int off = 1; off < 256; off <<= 1) {
        int tmp = (t >= off) ? lds[t - off] : 0;
        __syncthreads();
        lds[t] += tmp;
        __syncthreads();
    }
    bsums[t] = lds[t] - v;               // exclusive block offsets
}

__global__ void scan3(int* __restrict__ ptr, const int* __restrict__ bsums) {
    int i = blockIdx.x * 256 + threadIdx.x;
    ptr[i] += bsums[blockIdx.x];
    if (i == 0) ptr[N_NODES] = E_E;
}

__global__ void scatter_kernel(const int* __restrict__ row, const int* __restrict__ col,
                               const int* __restrict__ ptr, int* __restrict__ cursor,
                               const float* __restrict__ dinv,
                               int* __restrict__ erow, float* __restrict__ edge_val) {
    int e = blockIdx.x * 256 + threadIdx.x;
    if (e < E_E) {
        int c = col[e], r = row[e];
        int p = ptr[c] + atomicAdd(&cursor[c], 1);
        erow[p] = r;
        edge_val[p] = dinv[c] * dinv[r];
    }
}

// ---------------- q/k projection + fused L2-normalize ----------------
// 512 blocks x 256 thr; block handles 128 nodes.
// wave 0: q cols 0..63 (head0), wave 1: q cols 64..127 (head1),
// wave 2: k head0, wave 3: k head1 -> per-node sumsq is a wave butterfly.
__global__ __launch_bounds__(256) void proj_kernel(
    const float* __restrict__ x,
    const float* __restrict__ Wq, const float* __restrict__ bq,
    const float* __restrict__ Wk, const float* __restrict__ bk,
    float* __restrict__ qs, float* __restrict__ ks) {
    __shared__ float xl[128 * 64];
    int t = threadIdx.x;
    int nb = blockIdx.x;
    const float4* x4 = (const float4*)(x + nb * 128 * 64);
    float4* xl4 = (float4*)xl;
    for (int i = t; i < 128 * 64 / 4; i += 256) xl4[i] = x4[i];
    __syncthreads();

    int col = t & 127;
    const float* W = (t < 128) ? Wq : Wk;
    float bias = (t < 128) ? bq[col] : bk[col];
    float* outp = (t < 128) ? qs : ks;
    float wc[64];
#pragma unroll
    for (int kk = 0; kk < 64; ++kk) wc[kk] = W[kk * 128 + col];

    for (int i = 0; i < 128; ++i) {
        const float4* xr = (const float4*)(xl + i * 64);
        float acc = bias;
#pragma unroll
        for (int k4 = 0; k4 < 16; ++k4) {
            float4 v = xr[k4];
            acc += v.x * wc[4 * k4] + v.y * wc[4 * k4 + 1] +
                   v.z * wc[4 * k4 + 2] + v.w * wc[4 * k4 + 3];
        }
        float sq = acc * acc;
#pragma unroll
        for (int off = 32; off > 0; off >>= 1) sq += __shfl_xor(sq, off);
        outp[(nb * 128 + i) * 128 + col] = acc * rsqrtf(sq);
    }
}

// ---------------- kvs = K^T X per (b,h); plus ksum, xsum ----------------
__global__ __launch_bounds__(256) void kvs_kernel(
    const float* __restrict__ ks, const float* __restrict__ x,
    float* __restrict__ kvs, float* __restrict__ ksum, float* __restrict__ xsum) {
    int bid = blockIdx.x;
    int chunk = bid & 7;
    int bh = bid >> 3;
    int b = bh >> 1, h = bh & 1;
    int t = threadIdx.x;
    int mrow = t >> 4, dcol = t & 15;
    int m0 = mrow * 4, d0 = dcol * 4;
    __shared__ float kl[32 * 64];
    __shared__ float xl[32 * 64];
    float acc[4][4] = {{0}};
    float ksacc[4] = {0, 0, 0, 0};
    float xsacc[4] = {0, 0, 0, 0};
    int node0 = b * NPG_ + chunk * 512;
    for (int s = 0; s < 16; ++s) {
        int nb = node0 + s * 32;
        for (int i = t; i < 512; i += 256) {
            int l = i >> 4, q = i & 15;
            ((float4*)kl)[i] = *(const float4*)(ks + (size_t)(nb + l) * 128 + h * 64 + q * 4);
        }
        const float4* xg = (const float4*)(x + (size_t)nb * 64);
        for (int i = t; i < 512; i += 256) ((float4*)xl)[i] = xg[i];
        __syncthreads();
        for (int l = 0; l < 32; ++l) {
            float4 kv = *(float4*)(kl + l * 64 + m0);
            float4 xv = *(float4*)(xl + l * 64 + d0);
            float kk[4] = {kv.x, kv.y, kv.z, kv.w};
            float xx[4] = {xv.x, xv.y, xv.z, xv.w};
#pragma unroll
            for (int i = 0; i < 4; ++i)
#pragma unroll
                for (int j = 0; j < 4; ++j) acc[i][j] += kk[i] * xx[j];
            if (dcol == 0) {
#pragma unroll
                for (int i = 0; i < 4; ++i) ksacc[i] += kk[i];
            }
            if (mrow == 0) {
#pragma unroll
                for (int j = 0; j < 4; ++j) xsacc[j] += xx[j];
            }
        }
        __syncthreads();
    }
#pragma unroll
    for (int i = 0; i < 4; ++i)
#pragma unroll
        for (int j = 0; j < 4; ++j)
            atomicAdd(&kvs[(bh * 64 + m0 + i) * 64 + d0 + j], acc[i][j]);
    if (dcol == 0) {
#pragma unroll
        for (int i = 0; i < 4; ++i) atomicAdd(&ksum[bh * 64 + m0 + i], ksacc[i]);
    }
    if (mrow == 0 && h == 0) {
#pragma unroll
        for (int j = 0; j < 4; ++j) atomicAdd(&xsum[b * 64 + d0 + j], xsacc[j]);
    }
}

// ---------------- attention output: block = 128 nodes x 1 head ----------------
// Q-tile in LDS (broadcast reads), kvs column in regs: 4 FMA per ds_read_b128.
__global__ __launch_bounds__(256) void attn_kernel(
    const float* __restrict__ qs, const float* __restrict__ kvs,
    const float* __restrict__ ksum, const float* __restrict__ xsum,
    float* __restrict__ attn) {
    __shared__ float ql[128 * 64];
    int bid = blockIdx.x;
    int h = bid & 1;
    int nb = (bid >> 1) * 128;
    int b = nb >> 12;
    int bh = b * 2 + h;
    int t = threadIdx.x;
    int lane = t & 63;
    for (int i = t; i < 128 * 16; i += 256) {
        int r = i >> 4, q4 = i & 15;
        ((float4*)ql)[i] = *(const float4*)(qs + (size_t)(nb + r) * 128 + h * 64 + q4 * 4);
    }
    float kvreg[64];
    const float* kvp = kvs + bh * 4096 + lane;
#pragma unroll
    for (int m = 0; m < 64; ++m) kvreg[m] = kvp[m * 64];
    float ksreg = ksum[bh * 64 + lane];
    float xs_d = xsum[b * 64 + lane];
    __syncthreads();
    int nslot = t >> 6;
    for (int nn = 0; nn < 32; ++nn) {
        int node = nn * 4 + nslot;
        const float* qrow = ql + node * 64;
        float p = qrow[lane] * ksreg;
#pragma unroll
        for (int off = 32; off > 0; off >>= 1) p += __shfl_xor(p, off);
        float den = p + 16.0f;
        float acc = 0.f;
#pragma unroll
        for (int m4 = 0; m4 < 16; ++m4) {
            float4 qv = *(const float4*)(qrow + m4 * 4);
            acc += qv.x * kvreg[4 * m4] + qv.y * kvreg[4 * m4 + 1] +
                   qv.z * kvreg[4 * m4 + 2] + qv.w * kvreg[4 * m4 + 3];
        }
        attn[(size_t)(nb + node) * 128 + h * 64 + lane] = (acc + xs_d) / den;
    }
}

// ---------------- GCN step: one wave per node, float2 per lane ----------------
// XCD-chunked swizzle: each XCD owns 2 contiguous graphs (2MB gather set -> L2).
// FIRST variant reads x [N,64] directly (xs0 = broadcast of x over heads).
template <int FIRST>
__global__ __launch_bounds__(256) void gcn_kernel(
    const float* __restrict__ xin, const float* __restrict__ attn,
    const int* __restrict__ ptr, const int* __restrict__ erow,
    const float* __restrict__ edge_val, float* __restrict__ xout) {
    int bid = blockIdx.x;
    int lbid = (bid & 7) * (N_NODES / 4 / 8) + (bid >> 3);
    int t = threadIdx.x;
    int n = lbid * 4 + (t >> 6);
    int lane = t & 63;
    int c = lane * 2;
    int cx = FIRST ? (c & 63) : c;
    int ldx = FIRST ? 64 : 128;
    int e0 = ptr[n], e1 = ptr[n + 1];
    float2 acc = make_float2(0.f, 0.f);
    for (int e = e0; e < e1; ++e) {
        int r = erow[e];
        float v = edge_val[e];
        float2 xv = *(const float2*)(xin + (size_t)r * ldx + cx);
        acc.x += v * xv.x;
        acc.y += v * xv.y;
    }
    float2 self = *(const float2*)(xin + (size_t)n * ldx + cx);
    size_t idx = (size_t)n * 128 + c;
    float2 at = *(const float2*)(attn + idx);
    float2 o;
    o.x = self.x + 0.5f * acc.x + 0.5f * at.x;
    o.y = self.y + 0.5f * acc.y + 0.5f * at.y;
    *(float2*)(xout + idx) = o;
}

// ---------------- output projection: (xs @ Wo + bo)/H ----------------
__global__ __launch_bounds__(256) void out_kernel(
    const float* __restrict__ xs, const float* __restrict__ Wo,
    const float* __restrict__ bo, float* __restrict__ out) {
    __shared__ float wl[128 * 64];
    __shared__ float bl[64];
    int t = threadIdx.x;
    for (int i = t; i < 128 * 64 / 4; i += 256) ((float4*)wl)[i] = ((const float4*)Wo)[i];
    if (t < 64) bl[t] = bo[t];
    __syncthreads();
    int j = t & 63, ng = t >> 6;
    int nbase = blockIdx.x * 64;
    for (int it = 0; it < 16; ++it) {
        int n = nbase + it * 4 + ng;
        const float4* xr4 = (const float4*)(xs + (size_t)n * 128);
        float acc = bl[j];
#pragma unroll
        for (int k4 = 0; k4 < 32; ++k4) {
            float4 v = xr4[k4];
            acc += v.x * wl[(4 * k4 + 0) * 64 + j] + v.y * wl[(4 * k4 + 1) * 64 + j] +
                   v.z * wl[(4 * k4 + 2) * 64 + j] + v.w * wl[(4 * k4 + 3) * 64 + j];
        }
        out[(size_t)n * 64 + j] = acc * 0.5f;   // 1/H
    }
}

// ---------------- launch ----------------

extern "C" void kernel_launch(void* const* d_in, const int* in_sizes, int n_in,
                              void* d_out, int out_size, void* d_ws, size_t ws_size,
                              hipStream_t stream) {
    const float* x  = (const float*)d_in[0];
    const int* ei   = (const int*)d_in[1];
    const float* Wq = (const float*)d_in[3];
    const float* bq = (const float*)d_in[4];
    const float* Wk = (const float*)d_in[5];
    const float* bk = (const float*)d_in[6];
    const float* Wo = (const float*)d_in[7];
    const float* bo = (const float*)d_in[8];
    float* out = (float*)d_out;

    const int* row = ei;
    const int* col = ei + E_E;

    // workspace layout
    float* qs    = (float*)d_ws;                 // N*HD   (later xsA)
    float* ksatt = qs + (size_t)N_NODES * HD;    // N*HD   (ks, later attn)
    float* xsB   = ksatt + (size_t)N_NODES * HD; // N*HD
    float* kvs   = xsB + (size_t)N_NODES * HD;   // 32*64*64
    float* ksum  = kvs + 131072;                 // 2048
    float* xsum  = ksum + 2048;                  // 1024
    float* dinv  = xsum + 1024;                  // N
    int* degi    = (int*)(dinv + N_NODES);       // N
    int* ptr     = degi + N_NODES;               // N+1
    int* bsums   = ptr + N_NODES + 1;            // 256 (+pad)
    int* erow    = bsums + 512;                  // E
    float* edge_val = (float*)(erow + E_E);      // E

    hipMemsetAsync(degi, 0, (size_t)N_NODES * 4, stream);
    hipMemsetAsync(kvs, 0, (size_t)(131072 + 2048 + 1024) * 4, stream);

    // CSR build
    deg_kernel<<<E_E / 256, 256, 0, stream>>>(col, degi);
    dinv_kernel<<<N_NODES / 256, 256, 0, stream>>>(degi, dinv);
    scan1<<<N_NODES / 256, 256, 0, stream>>>(degi, ptr, bsums);
    scan2<<<1, 256, 0, stream>>>(bsums);
    scan3<<<N_NODES / 256, 256, 0, stream>>>(ptr, bsums);
    hipMemsetAsync(degi, 0, (size_t)N_NODES * 4, stream);   // reuse as cursor
    scatter_kernel<<<E_E / 256, 256, 0, stream>>>(row, col, ptr, degi, dinv, erow, edge_val);

    // projections (norm fused)
    proj_kernel<<<512, 256, 0, stream>>>(x, Wq, bq, Wk, bk, qs, ksatt);

    // attention (loop-invariant)
    kvs_kernel<<<256, 256, 0, stream>>>(ksatt, x, kvs, ksum, xsum);
    attn_kernel<<<1024, 256, 0, stream>>>(qs, kvs, ksum, xsum, ksatt);

    // 4 GCN steps; iter 1 reads x directly (xs0 = broadcast x), ping-pong after
    gcn_kernel<1><<<N_NODES / 4, 256, 0, stream>>>(x, ksatt, ptr, erow, edge_val, qs);
    gcn_kernel<0><<<N_NODES / 4, 256, 0, stream>>>(qs, ksatt, ptr, erow, edge_val, xsB);
    gcn_kernel<0><<<N_NODES / 4, 256, 0, stream>>>(xsB, ksatt, ptr, erow, edge_val, qs);
    gcn_kernel<0><<<N_NODES / 4, 256, 0, stream>>>(qs, ksatt, ptr, erow, edge_val, xsB);

    // output projection
    out_kernel<<<1024, 256, 0, stream>>>(xsB, Wo, bo, out);
}